// Round 7
// baseline (578.916 us; speedup 1.0000x reference)
//
#include <hip/hip_runtime.h>
#include <stdint.h>

typedef __attribute__((ext_vector_type(4))) float floatx4;
typedef __attribute__((ext_vector_type(8))) short short8;
typedef unsigned short ushort_t;

#define DEVI __device__ __forceinline__

// Problem constants
constexpr int Bc   = 4;
constexpr int Sc   = 1024;
constexpr int Hc   = 4096;
constexpr int NHc  = 32;
constexpr int NKVc = 8;
constexpr int Dc   = 128;
constexpr int QKVO = 6144;           // NH*D + 2*NKV*D
constexpr int Mc   = Bc * Sc;        // 4096 tokens

DEVI ushort_t f2bf(float f) {
  union { float f; unsigned u; } x; x.f = f;
  unsigned u = x.u;
  u += 0x7fffu + ((u >> 16) & 1u);   // RNE
  return (ushort_t)(u >> 16);
}

DEVI short8 cvt8(floatx4 a, floatx4 b) {
  short8 r;
  r[0] = (short)f2bf(a[0]); r[1] = (short)f2bf(a[1]);
  r[2] = (short)f2bf(a[2]); r[3] = (short)f2bf(a[3]);
  r[4] = (short)f2bf(b[0]); r[5] = (short)f2bf(b[1]);
  r[6] = (short)f2bf(b[2]); r[7] = (short)f2bf(b[3]);
  return r;
}

DEVI void load_lds16(const ushort_t* g, ushort_t* l) {
  __builtin_amdgcn_global_load_lds(
      (const __attribute__((address_space(1))) void*)g,
      (__attribute__((address_space(3))) void*)l, 16, 0, 0);
}

#define BARRIER()  asm volatile("s_barrier" ::: "memory")
#define VMCNT(n)   asm volatile("s_waitcnt vmcnt(" #n ")" ::: "memory")

// ---------------------------------------------------------------------------
// f32 -> bf16 plain convert (8 elems/thread)
// ---------------------------------------------------------------------------
__global__ __launch_bounds__(256)
void cvt_bf16(const float* __restrict__ src, ushort_t* __restrict__ dst, int n8)
{
  const int i = blockIdx.x * 256 + threadIdx.x;
  if (i >= n8) return;
  const floatx4 f0 = *(const floatx4*)(src + (size_t)i * 8);
  const floatx4 f1 = *(const floatx4*)(src + (size_t)i * 8 + 4);
  *(short8*)(dst + (size_t)i * 8) = cvt8(f0, f1);
}

// ---------------------------------------------------------------------------
// transpose + convert: src[R][C] f32 -> dst[C][R] bf16.  64x64 tiles.
// ---------------------------------------------------------------------------
__global__ __launch_bounds__(256)
void transpose_cvt(const float* __restrict__ src, ushort_t* __restrict__ dst,
                   int R, int C)
{
  __shared__ float ts[64][67];
  const int cb = C >> 6;
  const int r0 = (blockIdx.x / cb) << 6;
  const int c0 = (blockIdx.x % cb) << 6;
  const int t  = threadIdx.x;

  const int lr = t >> 4, lc = (t & 15) << 2;
#pragma unroll
  for (int i = 0; i < 4; ++i) {
    const floatx4 v = *(const floatx4*)(src + (size_t)(r0 + lr + 16 * i) * C + c0 + lc);
#pragma unroll
    for (int j = 0; j < 4; ++j) ts[lr + 16 * i][lc + j] = v[j];
  }
  __syncthreads();

  const int c     = ((t >> 6) << 4) + ((t & 63) >> 2);
  const int chunk = t & 3;
  short8 t0, t1;
#pragma unroll
  for (int k = 0; k < 8; ++k) t0[k] = (short)f2bf(ts[chunk * 16 + k][c]);
#pragma unroll
  for (int k = 0; k < 8; ++k) t1[k] = (short)f2bf(ts[chunk * 16 + 8 + k][c]);
  ushort_t* dp = dst + (size_t)(c0 + c) * R + r0 + chunk * 16;
  *(short8*)dp       = t0;
  *(short8*)(dp + 8) = t1;
}

// ---------------------------------------------------------------------------
// V transpose (bf16 -> bf16): qkv[b][s][5120 + hkv*128 + d] -> vt[b][hkv][d][s]
// ---------------------------------------------------------------------------
__global__ __launch_bounds__(256)
void v_transpose(const ushort_t* __restrict__ qkv, ushort_t* __restrict__ vt)
{
  __shared__ ushort_t ts[64][72];
  const int bid = blockIdx.x;
  const int db  = bid & 1;
  const int sb  = (bid >> 1) & 15;
  const int hkv = (bid >> 5) & 7;
  const int b   = bid >> 8;
  const int t   = threadIdx.x;

  const ushort_t* src = qkv + (size_t)(b * Sc + sb * 64) * QKVO
                        + (NHc * Dc + NKVc * Dc) + hkv * Dc + db * 64;
  const int lr = t >> 3, lc = (t & 7) * 8;
  *(short8*)&ts[lr][lc]      = *(const short8*)(src + (size_t)lr * QKVO + lc);
  *(short8*)&ts[lr + 32][lc] = *(const short8*)(src + (size_t)(lr + 32) * QKVO + lc);
  __syncthreads();

  ushort_t* dst = vt + ((size_t)(b * NKVc + hkv) * Dc + db * 64) * Sc + sb * 64;
  const int dr  = t >> 2;
  const int sc0 = (t & 3) * 16;
  short8 o0, o1;
#pragma unroll
  for (int k = 0; k < 8; ++k) o0[k] = (short)ts[sc0 + k][dr];
#pragma unroll
  for (int k = 0; k < 8; ++k) o1[k] = (short)ts[sc0 + 8 + k][dr];
  *(short8*)(dst + (size_t)dr * Sc + sc0)     = o0;
  *(short8*)(dst + (size_t)dr * Sc + sc0 + 8) = o1;
}

// ---------------------------------------------------------------------------
// 256x256 deep-pipeline GEMM: C[M,N] = A[M,K] * BT[N,K]^T.
// 512 thr = 8 waves (2M x 4N); wave owns 128x64.  BK=64, dbuf LDS 128KB.
// All 8 next-tile gload_lds issued at phase-0 start; counted vmcnt with
// 4-6 phase force distance:
//   ledger (per thread, 2 loads/group): S0S1=A-MLO  S2S3=B-NLO  S4S5=A-MHI
//   S6S7=B-NHI, all issued at ph0.  end-ph0 vmcnt(10) forces prev A-MHI;
//   end-ph1 vmcnt(8) forces prev B-NHI; end-ph3 vmcnt(4) forces cur A-MLO+B-NLO.
// Phases: ph0 M03xNev (reads A-MLO+Bev), ph1 M47xNev (reads A-MHI),
//         ph2 M47xNod (reads Bod), ph3 M03xNod (zero reads, A-MLO kept live).
// ---------------------------------------------------------------------------
template<bool OBF16>
__global__ __launch_bounds__(512, 2)
void gemm_nt8(const ushort_t* __restrict__ A, const ushort_t* __restrict__ BT,
              void* __restrict__ Cp, int M, int N, int K)
{
  __shared__ __align__(16) ushort_t As[2][256 * 64];
  __shared__ __align__(16) ushort_t Bs[2][256 * 64];

  const int nb  = N >> 8;
  const int nwg = (M >> 8) * nb;
  int bid = blockIdx.x;
  bid = (bid & 7) * (nwg >> 3) + (bid >> 3);     // XCD swizzle (nwg%8==0)
  const int bm = bid / nb, bn = bid % nb;
  const int m0 = bm << 8, n0 = bn << 8;

  const int tid  = threadIdx.x;
  const int wid  = tid >> 6, lane = tid & 63;
  const int wm   = wid >> 2, wn = wid & 3;       // wave grid 2x4
  const int fr   = lane & 15;
  const int g16  = (lane >> 4) << 4;             // frag k byte base
  const int rsw  = (fr & 7) << 4;                // read-side XOR
  const int l8   = lane >> 3;
  const int scol = ((lane & 7) ^ l8) << 3;       // pre-swizzled src col (ushorts)

  // staging bases: A load j covers the rows phase j/2 reads
  const int abase = ((wid >> 2) << 7) + ((wid & 3) << 4);  // {0..48}|{128..176}
  const int bbase = wid << 5;                              // 32-row bands

  const size_t Ks = (size_t)K;
  const ushort_t* ag = A  + (size_t)(m0 + abase + l8) * K + scol;
  const ushort_t* bg = BT + (size_t)(n0 + bbase + l8) * K + scol;

  const int rowA = (wm * 128 + fr) * 128;        // byte base for A frag reads
  const int rowB = (wn * 64 + fr) * 128;
  const int cb0  = g16 ^ rsw;
  const int cb1  = (64 + g16) ^ rsw;

  const floatx4 fz = {0.f, 0.f, 0.f, 0.f};
  floatx4 acc[8][4];
#pragma unroll
  for (int i = 0; i < 8; ++i)
#pragma unroll
    for (int f = 0; f < 4; ++f) acc[i][f] = fz;

  // stage all 8 loads for tile -> buf v, fixed program order (ledger!)
  auto STAGE = [&](int v, size_t kn) {
    load_lds16(ag + kn,            &As[v][(abase +  0) * 64]);  // S0 A-MLO
    load_lds16(ag +  8 * Ks + kn,  &As[v][(abase +  8) * 64]);  // S1
    load_lds16(bg + kn,            &Bs[v][(bbase +  0) * 64]);  // S2 B-NLO
    load_lds16(bg +  8 * Ks + kn,  &Bs[v][(bbase +  8) * 64]);  // S3
    load_lds16(ag + 64 * Ks + kn,  &As[v][(abase + 64) * 64]);  // S4 A-MHI
    load_lds16(ag + 72 * Ks + kn,  &As[v][(abase + 72) * 64]);  // S5
    load_lds16(bg + 16 * Ks + kn,  &Bs[v][(bbase + 16) * 64]);  // S6 B-NHI
    load_lds16(bg + 24 * Ks + kn,  &Bs[v][(bbase + 24) * 64]);  // S7
  };

  // ---- prologue: stage tile 0; force its MLO/NLO halves only ----
  STAGE(0, 0);
  VMCNT(4);
  BARRIER();

  const int NT = K >> 6;
  for (int kt = 0; kt < NT; ++kt) {
    const int u = kt & 1, v = u ^ 1;
    const char* Au = (const char*)&As[u][0];
    const char* Bu = (const char*)&Bs[u][0];
    const bool st  = (kt + 1 < NT);

#define LDA(i, ks) (*(const short8*)(Au + rowA + (i) * 2048 + ((ks) ? cb1 : cb0)))
#define LDB(f, ks) (*(const short8*)(Bu + rowB + (f) * 2048 + ((ks) ? cb1 : cb0)))
#define MFMA16(d, a0, a1, b0, b1)                                         \
    d = __builtin_amdgcn_mfma_f32_16x16x32_bf16(a0, b0, d, 0, 0, 0);      \
    d = __builtin_amdgcn_mfma_f32_16x16x32_bf16(a1, b1, d, 0, 0, 0);

    short8 aL[4][2], aH[4][2], bE[2][2], bO[2][2];

    // ---------------- phase 0: M0-3 x {N0,N2}; issue ALL next-tile loads ----
#pragma unroll
    for (int i = 0; i < 4; ++i) { aL[i][0] = LDA(i, 0); aL[i][1] = LDA(i, 1); }
#pragma unroll
    for (int f = 0; f < 2; ++f) { bE[f][0] = LDB(2 * f, 0); bE[f][1] = LDB(2 * f, 1); }
    if (st) STAGE(v, (size_t)(kt + 1) << 6);
    BARRIER();
    __builtin_amdgcn_s_setprio(1);
#pragma unroll
    for (int i = 0; i < 4; ++i)
#pragma unroll
      for (int f = 0; f < 2; ++f) { MFMA16(acc[i][2 * f], aL[i][0], aL[i][1], bE[f][0], bE[f][1]); }
    __builtin_amdgcn_s_setprio(0);
    if (st) { VMCNT(10); } else { VMCNT(2); }   // force prev tile's A-MHI
    BARRIER();

    // ---------------- phase 1: M4-7 x {N0,N2} ----------------
#pragma unroll
    for (int i = 0; i < 4; ++i) { aH[i][0] = LDA(4 + i, 0); aH[i][1] = LDA(4 + i, 1); }
    BARRIER();
    __builtin_amdgcn_s_setprio(1);
#pragma unroll
    for (int i = 0; i < 4; ++i)
#pragma unroll
      for (int f = 0; f < 2; ++f) { MFMA16(acc[4 + i][2 * f], aH[i][0], aH[i][1], bE[f][0], bE[f][1]); }
    __builtin_amdgcn_s_setprio(0);
    if (st) { VMCNT(8); } else { VMCNT(0); }    // force prev tile's B-NHI
    BARRIER();

    // ---------------- phase 2: M4-7 x {N1,N3} ----------------
#pragma unroll
    for (int f = 0; f < 2; ++f) { bO[f][0] = LDB(2 * f + 1, 0); bO[f][1] = LDB(2 * f + 1, 1); }
    BARRIER();
    __builtin_amdgcn_s_setprio(1);
#pragma unroll
    for (int i = 0; i < 4; ++i)
#pragma unroll
      for (int f = 0; f < 2; ++f) { MFMA16(acc[4 + i][2 * f + 1], aH[i][0], aH[i][1], bO[f][0], bO[f][1]); }
    __builtin_amdgcn_s_setprio(0);
    BARRIER();

    // ---------------- phase 3: M0-3 x {N1,N3} (A-MLO kept, zero reads) ----
    __builtin_amdgcn_s_setprio(1);
#pragma unroll
    for (int i = 0; i < 4; ++i)
#pragma unroll
      for (int f = 0; f < 2; ++f) { MFMA16(acc[i][2 * f + 1], aL[i][0], aL[i][1], bO[f][0], bO[f][1]); }
    __builtin_amdgcn_s_setprio(0);
    if (st) { VMCNT(4); }                       // force cur tile's A-MLO + B-NLO
    BARRIER();

#undef LDA
#undef LDB
#undef MFMA16
  }

  // ---- epilogue ----
  const int r4 = (lane >> 4) << 2;
#pragma unroll
  for (int i = 0; i < 8; ++i) {
#pragma unroll
    for (int rr = 0; rr < 4; ++rr) {
      const size_t row = (size_t)(m0 + wm * 128 + i * 16 + r4 + rr);
#pragma unroll
      for (int f = 0; f < 4; ++f) {
        const size_t col = (size_t)(n0 + wn * 64 + f * 16 + fr);
        if constexpr (OBF16)
          ((ushort_t*)Cp)[row * N + col] = f2bf(acc[i][f][rr]);
        else
          ((float*)Cp)[row * N + col] = acc[i][f][rr];
      }
    }
  }
}

// ---------------------------------------------------------------------------
// Flash attention, causal + ALiBi-sqrt (unchanged from R4/R5).
// ---------------------------------------------------------------------------
__global__ __launch_bounds__(256, 2)
void attn_fwd(const ushort_t* __restrict__ qkv,
              const ushort_t* __restrict__ vt,
              ushort_t* __restrict__ attn)
{
  __shared__ __align__(16) ushort_t Plds[4][32 * 40];

  const int bid = blockIdx.x;          // 512 blocks
  const int x   = bid & 7;
  const int p   = bid >> 3;
  const int j   = p & 15;
  const int g   = ((p >> 4) << 3) + x;
  const int b   = g >> 3;
  const int hkv = g & 7;

  const int tid  = threadIdx.x;
  const int wid  = tid >> 6, lane = tid & 63;
  const int h    = hkv * 4 + wid;
  const int fr   = lane & 15;
  const int kk8  = (lane >> 4) << 3;
  const int q4   = (lane >> 4) << 2;
  const float slope = exp2f(-0.25f * (float)(h + 1));
  const float scale = 0.08838834764831845f;

  const ushort_t* qp  = qkv + (size_t)b * Sc * QKVO + (size_t)h * Dc;
  const ushort_t* kp  = qkv + (size_t)b * Sc * QKVO + NHc * Dc + (size_t)hkv * Dc;
  const ushort_t* vtp = vt + (size_t)(b * NKVc + hkv) * Dc * Sc;
  ushort_t* myP = &Plds[wid][0];

  const floatx4 fz = {0.f, 0.f, 0.f, 0.f};

  auto process = [&](const int qb) {
    short8 qf[2][4];
#pragma unroll
    for (int t = 0; t < 2; ++t) {
      const int qrow = qb * 32 + t * 16 + fr;
#pragma unroll
      for (int s = 0; s < 4; ++s)
        qf[t][s] = *(const short8*)(qp + (size_t)qrow * QKVO + s * 32 + kk8);
    }

    floatx4 o[2][8];
#pragma unroll
    for (int t = 0; t < 2; ++t)
#pragma unroll
      for (int jj = 0; jj < 8; ++jj) o[t][jj] = fz;
    float mrow[2][4], lrow[2][4];
#pragma unroll
    for (int t = 0; t < 2; ++t)
#pragma unroll
      for (int rr = 0; rr < 4; ++rr) { mrow[t][rr] = -1e30f; lrow[t][rr] = 0.f; }

    for (int kb = 0; kb <= qb; ++kb) {
      floatx4 s_[2][2];
      s_[0][0] = fz; s_[0][1] = fz; s_[1][0] = fz; s_[1][1] = fz;
#pragma unroll
      for (int half = 0; half < 2; ++half) {
        const int kcol = kb * 32 + half * 16 + fr;
#pragma unroll
        for (int s = 0; s < 4; ++s) {
          const short8 kf = *(const short8*)(kp + (size_t)kcol * QKVO + s * 32 + kk8);
          s_[0][half] = __builtin_amdgcn_mfma_f32_16x16x32_bf16(qf[0][s], kf, s_[0][half], 0, 0, 0);
          s_[1][half] = __builtin_amdgcn_mfma_f32_16x16x32_bf16(qf[1][s], kf, s_[1][half], 0, 0, 0);
        }
      }

      short8 vf[8];
#pragma unroll
      for (int jj = 0; jj < 8; ++jj)
        vf[jj] = *(const short8*)(vtp + (size_t)(jj * 16 + fr) * Sc + kb * 32 + kk8);

#pragma unroll
      for (int t = 0; t < 2; ++t)
#pragma unroll
        for (int rr = 0; rr < 4; ++rr) {
          const int qg  = qb * 32 + t * 16 + q4 + rr;
          const int dk0 = qg - (kb * 32 + fr);
          const int dk1 = dk0 - 16;
          s_[t][0][rr] = (dk0 >= 0)
              ? s_[t][0][rr] * scale - slope * sqrtf((float)dk0) : -1e30f;
          s_[t][1][rr] = (dk1 >= 0)
              ? s_[t][1][rr] * scale - slope * sqrtf((float)dk1) : -1e30f;
        }

      float pmv[2][4];
#pragma unroll
      for (int t = 0; t < 2; ++t)
#pragma unroll
        for (int rr = 0; rr < 4; ++rr) {
          float pm = fmaxf(s_[t][0][rr], s_[t][1][rr]);
#pragma unroll
          for (int m = 1; m < 16; m <<= 1) pm = fmaxf(pm, __shfl_xor(pm, m));
          pmv[t][rr] = pm;
        }

      int need = 0;
#pragma unroll
      for (int t = 0; t < 2; ++t)
#pragma unroll
        for (int rr = 0; rr < 4; ++rr)
          need |= (pmv[t][rr] > mrow[t][rr] + 8.f) ? 1 : 0;
      if (__any(need)) {
#pragma unroll
        for (int t = 0; t < 2; ++t)
#pragma unroll
          for (int rr = 0; rr < 4; ++rr) {
            const float mnew = fmaxf(mrow[t][rr], pmv[t][rr]);
            const float corr = __expf(mrow[t][rr] - mnew);
            lrow[t][rr] *= corr;
            mrow[t][rr] = mnew;
#pragma unroll
            for (int jj = 0; jj < 8; ++jj) o[t][jj][rr] *= corr;
          }
      }

#pragma unroll
      for (int t = 0; t < 2; ++t)
#pragma unroll
        for (int rr = 0; rr < 4; ++rr) {
          const float p0 = __expf(s_[t][0][rr] - mrow[t][rr]);
          const float p1 = __expf(s_[t][1][rr] - mrow[t][rr]);
          lrow[t][rr] += p0 + p1;
          myP[(t * 16 + q4 + rr) * 40 + fr]      = f2bf(p0);
          myP[(t * 16 + q4 + rr) * 40 + 16 + fr] = f2bf(p1);
        }
      short8 pa[2];
      pa[0] = *(const short8*)&myP[fr * 40 + kk8];
      pa[1] = *(const short8*)&myP[(16 + fr) * 40 + kk8];

#pragma unroll
      for (int jj = 0; jj < 8; ++jj) {
        o[0][jj] = __builtin_amdgcn_mfma_f32_16x16x32_bf16(pa[0], vf[jj], o[0][jj], 0, 0, 0);
        o[1][jj] = __builtin_amdgcn_mfma_f32_16x16x32_bf16(pa[1], vf[jj], o[1][jj], 0, 0, 0);
      }
    }

#pragma unroll
    for (int t = 0; t < 2; ++t)
#pragma unroll
      for (int rr = 0; rr < 4; ++rr) {
        float rs = lrow[t][rr];
#pragma unroll
        for (int m = 1; m < 16; m <<= 1) rs += __shfl_xor(rs, m);
        const float inv = 1.f / rs;
        const size_t tok = (size_t)b * Sc + qb * 32 + t * 16 + q4 + rr;
#pragma unroll
        for (int jj = 0; jj < 8; ++jj)
          attn[tok * (size_t)(NHc * Dc) + h * Dc + jj * 16 + fr] = f2bf(o[t][jj][rr] * inv);
      }
  };

  process(31 - j);
  process(j);
}

// ---------------------------------------------------------------------------
extern "C" void kernel_launch(void* const* d_in, const int* in_sizes, int n_in,
                              void* d_out, int out_size, void* d_ws, size_t ws_size,
                              hipStream_t stream)
{
  const float* hidden = (const float*)d_in[0];
  const float* w_qkv  = (const float*)d_in[1];
  const float* w_o    = (const float*)d_in[2];
  float* out = (float*)d_out;

  // workspace layout (bf16 elems): 134.2 MB total
  ushort_t* wqT   = (ushort_t*)d_ws;                   // [6144][4096]  50.3MB
  ushort_t* hidb  = wqT + (size_t)QKVO * Hc;           // [4096][4096]  33.6MB
  ushort_t* qkvb  = hidb + (size_t)Mc * Hc;            // [4096][6144]  50.3MB
  ushort_t* attnb = hidb;                              // reuse after GEMM1
  ushort_t* woT   = wqT;                               // reuse after GEMM1
  ushort_t* vtb   = wqT + (size_t)Mc * Hc;             // reuse: wqT+33.6MB, 8.4MB

  // 1) hidden -> bf16
  cvt_bf16<<<dim3((Mc * Hc / 8) / 256), dim3(256), 0, stream>>>(
      hidden, hidb, Mc * Hc / 8);
  // 2) w_qkv^T -> bf16  [6144][4096]
  transpose_cvt<<<dim3((Hc / 64) * (QKVO / 64)), dim3(256), 0, stream>>>(
      w_qkv, wqT, Hc, QKVO);
  // 3) qkv = hidden @ w_qkv
  gemm_nt8<true><<<dim3((Mc / 256) * (QKVO / 256)), dim3(512), 0, stream>>>(
      hidb, wqT, qkvb, Mc, QKVO, Hc);
  // 4) V -> VT  [b][hkv][d][s]
  v_transpose<<<dim3(1024), dim3(256), 0, stream>>>(qkvb, vtb);
  // 5) attention
  attn_fwd<<<dim3(512), dim3(256), 0, stream>>>(qkvb, vtb, attnb);
  // 6) w_o^T -> bf16  [4096][4096]
  transpose_cvt<<<dim3((Hc / 64) * (Hc / 64)), dim3(256), 0, stream>>>(
      w_o, woT, Hc, Hc);
  // 7) out = attn @ w_o
  gemm_nt8<false><<<dim3((Mc / 256) * (Hc / 256)), dim3(512), 0, stream>>>(
      attnb, woT, out, Mc, Hc, Hc);
}